// Round 12
// baseline (293.963 us; speedup 1.0000x reference)
//
#include <hip/hip_runtime.h>
#include <hip/hip_bf16.h>

#define N_NODES 50000
#define N_EDGES 800000
#define NFEAT   8
#define NHID    128
#define NCLASS  112
#define SEG_EPS 1e-16f
#define BN_EPS  1e-5f
#define CAP     64
#define MACRO_TILES 782
#define NODE_RANGE 6250
#define FILL_CHUNK 4096    // 256 thr x 16 edges (ILP: ~4 independent atomic chains/thread)
#define FILL_CHUNKS 196    // ceil(800000 / 4096)
#define FSFD_BLOCKS 196
#define SG_GRID 3200
#define SG_IT 4
#define ATT_GRID 3200
#define ATT_IT 4
#define OUT_GRID 3200
#define OUT_IT 4

#define FILLB (FILL_CHUNKS * 8)        // 1568
#define FSFD0 FILLB                    // 1568
#define W2P0  (FSFD0 + FSFD_BLOCKS)    // 1764
#define W2T0  (W2P0 + 64)              // 1828
#define WGT0  (W2T0 + 32)              // 1860
#define GRID_FILL (WGT0 + 28)          // 1888

typedef __hip_bfloat16 bf16;
typedef __attribute__((ext_vector_type(8))) short short8;
typedef __attribute__((ext_vector_type(4))) float f32x4;
typedef __attribute__((ext_vector_type(4))) unsigned int u32x4;

__device__ __forceinline__ float bfbits2f(unsigned int lo16) {
    union { unsigned int u; float f; } c; c.u = lo16 << 16; return c.f;
}

__device__ __forceinline__ unsigned int pack_bf2(float a, float b) {
    union { unsigned int u; bf16 h[2]; } t;
    t.h[0] = __float2bfloat16(a);
    t.h[1] = __float2bfloat16(b);
    return t.u;
}

// ======= bucketed CSR build (XCD-partitioned) + fsfd + weight prep =======
// Fill branch: 16 edges/thread, all edge data loaded vectorized upfront,
// payloads precomputed -> ~4 independent atomic+store chains per thread to
// hide the ~300cy atomic round-trip (fill is latency-bound: R7 counters show
// VALU 4% / HBM 23% / Occ 58%, nothing saturated).
// r10 lesson: NO per-block __threadfence in bulk kernels (per-XCD L2
// writeback storms); producer->consumer ordering via kernel boundaries only.
__global__ __launch_bounds__(256)
void k_fill_fsfd(const int* __restrict__ src, const int* __restrict__ dst,
                 const float* __restrict__ ewt,
                 int* __restrict__ cnt, unsigned int* __restrict__ bucket,
                 const float* __restrict__ x, const float* __restrict__ W1,
                 const float* __restrict__ a1s, const float* __restrict__ a1d,
                 float* __restrict__ xf,
                 const float* __restrict__ W2,
                 const float* __restrict__ a2s, const float* __restrict__ a2d,
                 float* __restrict__ w2s, float* __restrict__ w2d,
                 const float* __restrict__ Wg,
                 bf16* __restrict__ W2t, bf16* __restrict__ Wgt) {
    __shared__ float sw[16];
    __shared__ float ps[4], pd[4];
    const int t = threadIdx.x;
    if (blockIdx.x < FILLB) {
        const int range = blockIdx.x & 7;
        const int chunk = blockIdx.x >> 3;
        const int lo = range * NODE_RANGE, hi = lo + NODE_RANGE;
        const int e0 = chunk * FILL_CHUNK + t * 16;
        if (e0 >= N_EDGES) return;        // 800000 % 16 == 0: all-or-nothing
        int dd[16]; int ss[16]; float ww[16];
#pragma unroll
        for (int v4 = 0; v4 < 4; v4++) {
            const int4 dv = *(const int4*)&dst[e0 + v4 * 4];
            const int4 sv = *(const int4*)&src[e0 + v4 * 4];
            const float4 wv = *(const float4*)&ewt[e0 + v4 * 4];
            dd[v4*4+0] = dv.x; dd[v4*4+1] = dv.y; dd[v4*4+2] = dv.z; dd[v4*4+3] = dv.w;
            ss[v4*4+0] = sv.x; ss[v4*4+1] = sv.y; ss[v4*4+2] = sv.z; ss[v4*4+3] = sv.w;
            ww[v4*4+0] = wv.x; ww[v4*4+1] = wv.y; ww[v4*4+2] = wv.z; ww[v4*4+3] = wv.w;
        }
        unsigned int pl[16];
#pragma unroll
        for (int i = 0; i < 16; i++)
            pl[i] = ((unsigned int)ss[i] << 15) |
                    (unsigned int)(ww[i] * 32767.f + 0.5f);
#pragma unroll
        for (int i = 0; i < 16; i++) {
            int d = dd[i];
            if (d < lo || d >= hi) continue;
            int slot = atomicAdd(&cnt[d], 1);
            if (slot < CAP) bucket[d * CAP + slot] = pl[i];
        }
        return;
    }
    if (blockIdx.x < W2P0) {
        const int w = t >> 6, lane = t & 63;
#pragma unroll
        for (int dd = 0; dd < 4; dd++) {
            int dot = w + dd * 4;
            int k = dot & 7;
            const float* a = (dot < 8) ? a1s : a1d;
            float v = W1[k * NHID + lane] * a[lane] + W1[k * NHID + 64 + lane] * a[64 + lane];
#pragma unroll
            for (int off = 32; off > 0; off >>= 1) v += __shfl_down(v, off);
            if (lane == 0) sw[dot] = v;
        }
        __syncthreads();
        const int i = (blockIdx.x - FSFD0) * 256 + t;
        if (i < N_NODES) {
            const float4 x0 = ((const float4*)x)[i * 2];
            const float4 x1 = ((const float4*)x)[i * 2 + 1];
            float fsv = x0.x*sw[0] + x0.y*sw[1] + x0.z*sw[2] + x0.w*sw[3]
                      + x1.x*sw[4] + x1.y*sw[5] + x1.z*sw[6] + x1.w*sw[7];
            float fdv = x0.x*sw[8] + x0.y*sw[9] + x0.z*sw[10] + x0.w*sw[11]
                      + x1.x*sw[12] + x1.y*sw[13] + x1.z*sw[14] + x1.w*sw[15];
            float4* xr = (float4*)&xf[(size_t)i * 16];
            xr[0] = x0;
            xr[1] = x1;
            xr[2] = make_float4(fsv, fdv, 0.f, 0.f);
        }
        return;
    }
    if (blockIdx.x < W2T0) {
        const int k = (blockIdx.x - W2P0) * 2 + (t >> 7);
        const int n = t & 127;
        float wv = W2[k * NHID + n];
        float vs = wv * a2s[n], vd = wv * a2d[n];
#pragma unroll
        for (int off = 32; off > 0; off >>= 1) { vs += __shfl_down(vs, off); vd += __shfl_down(vd, off); }
        const int wid = t >> 6;
        if ((t & 63) == 0) { ps[wid] = vs; pd[wid] = vd; }
        __syncthreads();
        if ((t & 127) == 0) { w2s[k] = ps[wid] + ps[wid + 1]; w2d[k] = pd[wid] + pd[wid + 1]; }
        return;
    }
    if (blockIdx.x < WGT0) {
        const int n = (blockIdx.x - W2T0) * 4 + (t >> 6);
        const int k2 = (t & 63) * 2;
        *(unsigned int*)&W2t[n * 128 + k2] = pack_bf2(W2[k2 * NHID + n], W2[(k2 + 1) * NHID + n]);
        return;
    }
    const int n = (blockIdx.x - WGT0) * 4 + (t >> 6);
    const int k2 = (t & 63) * 2;
    *(unsigned int*)&Wgt[n * 128 + k2] = pack_bf2(Wg[k2 * NCLASS + n], Wg[(k2 + 1) * NCLASS + n]);
}

// ===== sort + gather + y1 + BN partials, grid-strided 3200 x 4 iters =====
__global__ __launch_bounds__(256)
void k_sort_gather_y1(const int* __restrict__ cnt, unsigned int* __restrict__ bucket,
                      const float* __restrict__ xf, const float* __restrict__ W1,
                      bf16* __restrict__ y1,
                      float* __restrict__ Psum, float* __restrict__ Psq) {
    const int xcd = blockIdx.x & 7;
    const int wb  = blockIdx.x >> 3;
    const int t = threadIdx.x;
    const int q = t >> 6;
    const int lane = t & 63;
    float w1c0[8], w1c1[8];
#pragma unroll
    for (int k = 0; k < 8; k++) {
        const float2 wv = *(const float2*)&W1[k * NHID + 2 * lane];
        w1c0[k] = wv.x; w1c1[k] = wv.y;
    }
    float ls0 = 0.f, ls1 = 0.f, lq0 = 0.f, lq1 = 0.f;
    for (int it = 0; it < SG_IT; it++) {
        const int ni = (wb + it * 400) * 4 + q;
        if (ni >= NODE_RANGE) continue;
        const int d = xcd * NODE_RANGE + ni;
        const int deg = min(cnt[d], CAP);
        unsigned int v = (lane < deg) ? bucket[d * CAP + lane] : 0xFFFFFFFFu;
#pragma unroll
        for (int k = 2; k <= 64; k <<= 1) {
#pragma unroll
            for (int s = k >> 1; s > 0; s >>= 1) {
                unsigned int o = (unsigned int)__shfl_xor((int)v, s);
                bool keepmin = ((lane & s) == 0) == ((lane & k) == 0);
                v = keepmin ? min(v, o) : max(v, o);
            }
        }
        if (lane < deg) bucket[d * CAP + lane] = v;
        const int epair = lane >> 1;
        const int half  = lane & 1;
        const float fdd = xf[(size_t)d * 16 + 9];
        float4 acc = {0.f, 0.f, 0.f, 0.f};
        float den = 0.f;
        for (int base = 0; base < deg; base += 32) {
            int e = base + epair;
            unsigned int u = (unsigned int)__shfl((int)v, e);
            if (e < deg) {
                int s = u >> 15;
                const float4 xv = *(const float4*)&xf[(size_t)s * 16 + half * 4];
                float fsv = xf[(size_t)s * 16 + 8];       // same 64B line
                float f = fsv + fdd;
                float lr = f > 0.f ? f : 0.2f * f;
                float c = __expf(-lr);
                if (half == 0) den += c;
                acc.x += c * xv.x; acc.y += c * xv.y; acc.z += c * xv.z; acc.w += c * xv.w;
            }
        }
#pragma unroll
        for (int off = 2; off < 64; off <<= 1) {
            acc.x += __shfl_xor(acc.x, off);
            acc.y += __shfl_xor(acc.y, off);
            acc.z += __shfl_xor(acc.z, off);
            acc.w += __shfl_xor(acc.w, off);
            den   += __shfl_xor(den, off);
        }
        den += __shfl_xor(den, 1);
        float4 oth;
        oth.x = __shfl_xor(acc.x, 1);
        oth.y = __shfl_xor(acc.y, 1);
        oth.z = __shfl_xor(acc.z, 1);
        oth.w = __shfl_xor(acc.w, 1);
        const float r = 1.f / (den + SEG_EPS);
        float xa[8];
        if ((lane & 1) == 0) {
            xa[0]=acc.x*r; xa[1]=acc.y*r; xa[2]=acc.z*r; xa[3]=acc.w*r;
            xa[4]=oth.x*r; xa[5]=oth.y*r; xa[6]=oth.z*r; xa[7]=oth.w*r;
        } else {
            xa[0]=oth.x*r; xa[1]=oth.y*r; xa[2]=oth.z*r; xa[3]=oth.w*r;
            xa[4]=acc.x*r; xa[5]=acc.y*r; xa[6]=acc.z*r; xa[7]=acc.w*r;
        }
        float v0 = 0.f, v1 = 0.f;
#pragma unroll
        for (int k = 0; k < 8; k++) {
            v0 += xa[k] * w1c0[k];
            v1 += xa[k] * w1c1[k];
        }
        ((unsigned int*)y1)[(size_t)d * 64 + lane] = pack_bf2(v0, v1);
        ls0 += v0; lq0 += v0 * v0;
        ls1 += v1; lq1 += v1 * v1;
    }
    __shared__ float sred[4][64][2];
    sred[q][lane][0] = ls0;
    sred[q][lane][1] = ls1;
    __syncthreads();
    if (t < 128) {
        int ln = t >> 1, cp = t & 1;
        Psum[blockIdx.x * 128 + t] =
            ((sred[0][ln][cp] + sred[1][ln][cp]) + sred[2][ln][cp]) + sred[3][ln][cp];
    }
    __syncthreads();
    sred[q][lane][0] = lq0;
    sred[q][lane][1] = lq1;
    __syncthreads();
    if (t < 128) {
        int ln = t >> 1, cp = t & 1;
        Psq[blockIdx.x * 128 + t] =
            ((sred[0][ln][cp] + sred[1][ln][cp]) + sred[2][ln][cp]) + sred[3][ln][cp];
    }
}

// ===== fused BN reduction (SEPARATE dispatch): 16 workers + 1 finalizer =====
__global__ __launch_bounds__(256)
void k_reduce_fused(const float* __restrict__ Psum, const float* __restrict__ Psq,
                    int nIn, int chunk,
                    float* __restrict__ Qsum, float* __restrict__ Qsq,
                    const float* __restrict__ gamma, const float* __restrict__ beta,
                    float* __restrict__ scale, float* __restrict__ shift,
                    int* __restrict__ flag) {
    const int t = threadIdx.x;
    if (blockIdx.x < 16) {
        const int j = t & 127;
        const int h = t >> 7;
        const int u = blockIdx.x * 2 + h;
        const int b0 = u * chunk, b1 = min(b0 + chunk, nIn);
        float s = 0.f, q = 0.f;
#pragma unroll 8
        for (int b = b0; b < b1; b++) {
            s += Psum[b * 128 + j];
            q += Psq[b * 128 + j];
        }
        Qsum[u * 128 + j] = s;
        Qsq[u * 128 + j] = q;
        __threadfence();
        __syncthreads();
        if (t == 0) atomicAdd(flag, 1);
        return;
    }
    if (t == 0) { while (atomicAdd(flag, 0) < 16) { } }
    __syncthreads();
    __threadfence();
    const int j = t & 127;
    const int g = t >> 7;
    float s = 0.f, q = 0.f;
#pragma unroll
    for (int u = g * 16; u < g * 16 + 16; u++) {
        s += Qsum[u * 128 + j];
        q += Qsq[u * 128 + j];
    }
    __shared__ float Ls[2][128], Lq[2][128];
    Ls[g][j] = s; Lq[g][j] = q;
    __syncthreads();
    if (g == 0) {
        float st = Ls[0][j] + Ls[1][j];
        float qt = Lq[0][j] + Lq[1][j];
        float mu = st * (1.f / N_NODES);
        float var = qt * (1.f / N_NODES) - mu * mu;
        float rs = rsqrtf(var + BN_EPS);
        float ga = gamma[j];
        scale[j] = rs * ga;
        shift[j] = beta[j] - mu * rs * ga;
    }
    __syncthreads();
    if (t == 0) atomicExch(flag, 0);
}

// ===== MFMA GEMM v2: direct-A from global, prestaged bf16 B =====
template<int NCV, bool ATT>
__global__ __launch_bounds__(256)
void k_gemm_mfma(const bf16* __restrict__ Yin,
                 const float* __restrict__ scale, const float* __restrict__ shift,
                 const bf16* __restrict__ Wt_g,
                 bf16* __restrict__ hout,
                 const float* __restrict__ w2s, const float* __restrict__ w2d,
                 float* __restrict__ fs, float* __restrict__ fd) {
    constexpr int NT = NCV / 16;
    __shared__ bf16 Wt[NCV * 136];
    __shared__ float scb[128], shb[128];
    const int t = threadIdx.x;
    for (int idx = t; idx < NCV * 16; idx += 256) {
        int n = idx >> 4, c = idx & 15;
        *(u32x4*)&Wt[n * 136 + c * 8] = *(const u32x4*)&Wt_g[n * 128 + c * 8];
    }
    if (t < 128) { scb[t] = scale[t]; shb[t] = shift[t]; }
    const int lane = t & 63;
    const int m16 = lane & 15;
    const int g = lane >> 4;
    const int rg = t >> 6;
    short8 attb[4];
    if constexpr (ATT) {
#pragma unroll
        for (int kk = 0; kk < 4; kk++) {
            union { short8 s; unsigned int u[4]; } pk;
            if (m16 < 2) {
                const float* wv = (m16 == 0) ? w2s : w2d;
                const float4 f0 = *(const float4*)&wv[kk * 32 + g * 8];
                const float4 f1 = *(const float4*)&wv[kk * 32 + g * 8 + 4];
                pk.u[0] = pack_bf2(f0.x, f0.y);
                pk.u[1] = pack_bf2(f0.z, f0.w);
                pk.u[2] = pack_bf2(f1.x, f1.y);
                pk.u[3] = pack_bf2(f1.z, f1.w);
            } else {
                pk.u[0] = pk.u[1] = pk.u[2] = pk.u[3] = 0u;
            }
            attb[kk] = pk.s;
        }
    }
    __syncthreads();

    const int row0 = blockIdx.x * 64;
    const int arow = row0 + rg * 16 + m16;
    const bool rok = arow < N_NODES;
    f32x4 acc[NT];
#pragma unroll
    for (int c = 0; c < NT; c++) acc[c] = (f32x4){0.f, 0.f, 0.f, 0.f};
    f32x4 accA = (f32x4){0.f, 0.f, 0.f, 0.f};
#pragma unroll
    for (int kk = 0; kk < 4; kk++) {
        u32x4 u4 = rok
            ? *(const u32x4*)&((const unsigned int*)Yin)[(size_t)arow * 64 + kk * 16 + g * 4]
            : (u32x4){0u, 0u, 0u, 0u};
        const float4 s0 = *(const float4*)&scb[kk * 32 + g * 8];
        const float4 s1 = *(const float4*)&scb[kk * 32 + g * 8 + 4];
        const float4 h0 = *(const float4*)&shb[kk * 32 + g * 8];
        const float4 h1 = *(const float4*)&shb[kk * 32 + g * 8 + 4];
        const float scv[8] = {s0.x, s0.y, s0.z, s0.w, s1.x, s1.y, s1.z, s1.w};
        const float shv[8] = {h0.x, h0.y, h0.z, h0.w, h1.x, h1.y, h1.z, h1.w};
        union { short8 s; unsigned int u[4]; } A;
#pragma unroll
        for (int fq = 0; fq < 4; fq++) {
            unsigned int u = u4[fq];
            float v0 = bfbits2f(u & 0xFFFF) * scv[2*fq]   + shv[2*fq];   v0 = v0 > 0.f ? v0 : 0.01f * v0;
            float v1 = bfbits2f(u >> 16)    * scv[2*fq+1] + shv[2*fq+1]; v1 = v1 > 0.f ? v1 : 0.01f * v1;
            A.u[fq] = pack_bf2(v0, v1);
        }
#pragma unroll
        for (int c = 0; c < NT; c++) {
            short8 bfr = *(const short8*)&Wt[(c * 16 + m16) * 136 + kk * 32 + g * 8];
            acc[c] = __builtin_amdgcn_mfma_f32_16x16x32_bf16(A.s, bfr, acc[c], 0, 0, 0);
        }
        if constexpr (ATT)
            accA = __builtin_amdgcn_mfma_f32_16x16x32_bf16(A.s, attb[kk], accA, 0, 0, 0);
    }
    const int orow = row0 + rg * 16 + g * 4;
#pragma unroll
    for (int c = 0; c < NT; c++) {
#pragma unroll
        for (int r = 0; r < 4; r++) {
            int grow = orow + r;
            if (grow < N_NODES)
                hout[(size_t)grow * 128 + c * 16 + m16] = __float2bfloat16(acc[c][r]);
        }
    }
    if constexpr (ATT) {
        if (m16 < 2) {
            float* o = (m16 == 0) ? fs : fd;
#pragma unroll
            for (int r = 0; r < 4; r++) {
                int grow = orow + r;
                if (grow < N_NODES) o[grow] = accA[r];
            }
        }
    }
}

// ===== attention gather, 4-edges-per-wave dwordx4 (unroll 8) + BN stats =====
__global__ __launch_bounds__(256)
void k_gather_attn_bf(const int* __restrict__ cnt, const unsigned int* __restrict__ bucket,
                      const float* __restrict__ fs, const float* __restrict__ fd,
                      const bf16* __restrict__ h, bf16* __restrict__ y,
                      float* __restrict__ Psum, float* __restrict__ Psq) {
    const int xcd = blockIdx.x & 7;
    const int wb  = blockIdx.x >> 3;
    const int t = threadIdx.x;
    const int q = t >> 6;
    const int lane = t & 63;
    const int grp = lane >> 4;
    const int l = lane & 15;
    __shared__ int s_idx[4][CAP];
    __shared__ float s_e[4][CAP];
    __shared__ float sred[4][16][8];
    float ls[8], lq[8];
#pragma unroll
    for (int i = 0; i < 8; i++) { ls[i] = 0.f; lq[i] = 0.f; }

    for (int it = 0; it < ATT_IT; it++) {
        const int ni = (wb + it * 400) * 4 + q;
        if (ni >= NODE_RANGE) continue;
        const int d = xcd * NODE_RANGE + ni;
        const int deg = min(cnt[d], CAP);
        const float fdd = fd[d];
        if (lane < deg) {
            int s = bucket[d * CAP + lane] >> 15;
            float f = fs[s] + fdd;
            float lr = f > 0.f ? f : 0.2f * f;
            s_idx[q][lane] = s;
            s_e[q][lane] = __expf(-lr);
        }
        float a[8];
#pragma unroll
        for (int i = 0; i < 8; i++) a[i] = 0.f;
        float den = 0.f;
#pragma unroll 8
        for (int base = 0; base < deg; base += 4) {
            int k = base + grp;
            bool ev = k < deg;
            int kk = ev ? k : 0;
            float e = ev ? s_e[q][kk] : 0.f;
            int sidx = s_idx[q][kk];
            u32x4 u4 = *(const u32x4*)&((const unsigned int*)h)[(size_t)sidx * 64 + l * 4];
            den += e;
#pragma unroll
            for (int fq = 0; fq < 4; fq++) {
                unsigned int u = u4[fq];
                a[2*fq]   += e * bfbits2f(u & 0xFFFF);
                a[2*fq+1] += e * bfbits2f(u >> 16);
            }
        }
#pragma unroll
        for (int off = 16; off < 64; off <<= 1) {
#pragma unroll
            for (int i = 0; i < 8; i++) a[i] += __shfl_xor(a[i], off);
            den += __shfl_xor(den, off);
        }
        float r = 1.f / (den + SEG_EPS);
        if (lane < 16) {
            u32x4 pk;
#pragma unroll
            for (int fq = 0; fq < 4; fq++) {
                float v0 = a[2*fq] * r, v1 = a[2*fq+1] * r;
                pk[fq] = pack_bf2(v0, v1);
                ls[2*fq] += v0;   lq[2*fq] += v0 * v0;
                ls[2*fq+1] += v1; lq[2*fq+1] += v1 * v1;
            }
            *(u32x4*)&((unsigned int*)y)[(size_t)d * 64 + l * 4] = pk;
        }
    }
    if (lane < 16) {
#pragma unroll
        for (int i = 0; i < 8; i++) sred[q][l][i] = ls[i];
    }
    __syncthreads();
    if (t < 128) {
        int l16 = t >> 3, i8 = t & 7;
        Psum[blockIdx.x * 128 + t] =
            ((sred[0][l16][i8] + sred[1][l16][i8]) + sred[2][l16][i8]) + sred[3][l16][i8];
    }
    __syncthreads();
    if (lane < 16) {
#pragma unroll
        for (int i = 0; i < 8; i++) sred[q][l][i] = lq[i];
    }
    __syncthreads();
    if (t < 128) {
        int l16 = t >> 3, i8 = t & 7;
        Psq[blockIdx.x * 128 + t] =
            ((sred[0][l16][i8] + sred[1][l16][i8]) + sred[2][l16][i8]) + sred[3][l16][i8];
    }
}

// ===== final gather + epilogue: grid-strided 3200 x 4, unroll 8 =====
__global__ __launch_bounds__(256)
void k_gather_out_bf(const int* __restrict__ cnt, const unsigned int* __restrict__ bucket,
                     const bf16* __restrict__ sup, const float* __restrict__ bg,
                     float* __restrict__ out) {
    const int xcd = blockIdx.x & 7;
    const int wb  = blockIdx.x >> 3;
    const int t = threadIdx.x;
    const int q = t >> 6;
    const int lane = t & 63;
    const int grp = lane >> 4;
    const int l = lane & 15;
    __shared__ int s_idx[4][CAP];
    __shared__ float s_w[4][CAP];
    for (int it = 0; it < OUT_IT; it++) {
        const int ni = (wb + it * 400) * 4 + q;
        if (ni >= NODE_RANGE) continue;
        const int d = xcd * NODE_RANGE + ni;
        const int deg = min(cnt[d], CAP);
        if (lane < deg) {
            unsigned int b = bucket[d * CAP + lane];
            s_idx[q][lane] = b >> 15;
            s_w[q][lane] = (float)(b & 0x7FFF) * (1.f / (32767.f * 3.f));
        }
        float a[8];
#pragma unroll
        for (int i = 0; i < 8; i++) a[i] = 0.f;
#pragma unroll 8
        for (int base = 0; base < deg; base += 4) {
            int k = base + grp;
            bool ev = k < deg;
            int kk = ev ? k : 0;
            float w = ev ? s_w[q][kk] : 0.f;
            int sidx = s_idx[q][kk];
            u32x4 u4 = (l < 14)
                ? *(const u32x4*)&((const unsigned int*)sup)[(size_t)sidx * 64 + l * 4]
                : (u32x4){0u, 0u, 0u, 0u};
#pragma unroll
            for (int fq = 0; fq < 4; fq++) {
                unsigned int u = u4[fq];
                a[2*fq]   += w * bfbits2f(u & 0xFFFF);
                a[2*fq+1] += w * bfbits2f(u >> 16);
            }
        }
#pragma unroll
        for (int off = 16; off < 64; off <<= 1) {
#pragma unroll
            for (int i = 0; i < 8; i++) a[i] += __shfl_xor(a[i], off);
        }
        if (l < 14) {
            u32x4 us = *(const u32x4*)&((const unsigned int*)sup)[(size_t)d * 64 + l * 4];
            const float4 b0 = *(const float4*)&bg[l * 8];
            const float4 b1 = *(const float4*)&bg[l * 8 + 4];
            float4 o0, o1;
            o0.x = a[0] + bfbits2f(us[0] & 0xFFFF) * (2.f/3.f) + b0.x;
            o0.y = a[1] + bfbits2f(us[0] >> 16)    * (2.f/3.f) + b0.y;
            o0.z = a[2] + bfbits2f(us[1] & 0xFFFF) * (2.f/3.f) + b0.z;
            o0.w = a[3] + bfbits2f(us[1] >> 16)    * (2.f/3.f) + b0.w;
            o1.x = a[4] + bfbits2f(us[2] & 0xFFFF) * (2.f/3.f) + b1.x;
            o1.y = a[5] + bfbits2f(us[2] >> 16)    * (2.f/3.f) + b1.y;
            o1.z = a[6] + bfbits2f(us[3] & 0xFFFF) * (2.f/3.f) + b1.z;
            o1.w = a[7] + bfbits2f(us[3] >> 16)    * (2.f/3.f) + b1.w;
            *(float4*)&out[(size_t)d * NCLASS + l * 8]     = o0;
            *(float4*)&out[(size_t)d * NCLASS + l * 8 + 4] = o1;
        }
    }
}

extern "C" void kernel_launch(void* const* d_in, const int* in_sizes, int n_in,
                              void* d_out, int out_size, void* d_ws, size_t ws_size,
                              hipStream_t stream) {
    const float* x    = (const float*)d_in[0];
    const int*   ei   = (const int*)d_in[1];
    const float* ewt  = (const float*)d_in[2];
    const float* W1   = (const float*)d_in[3];
    const float* a1s  = (const float*)d_in[4];
    const float* a1d  = (const float*)d_in[5];
    const float* W2   = (const float*)d_in[6];
    const float* a2s  = (const float*)d_in[7];
    const float* a2d  = (const float*)d_in[8];
    const float* gam  = (const float*)d_in[9];
    const float* bet  = (const float*)d_in[10];
    const float* Wg   = (const float*)d_in[11];
    const float* bg   = (const float*)d_in[12];
    float* out = (float*)d_out;

    const int* src = ei;
    const int* dst = ei + N_EDGES;

    float* ws    = (float*)d_ws;
    bf16*  Yb    = (bf16*)ws;                       // [N,128] bf16 (y1, then y2)
    bf16*  Hb    = (bf16*)(ws + 3203072);           // [N,128] bf16 (h2 / support)
    unsigned int* bucket = (unsigned int*)(ws + 6403072);   // [N*64] packed
    float* fs    = ws + 10003072;                   // [N]
    float* fd    = ws + 10053072;                   // [N]
    int*   cnt   = (int*)(ws + 10103072);           // [N]
    int*   flags = (int*)(ws + 10153072);           // [4] (covered by memset)
    float* scale = ws + 10153076;                   // [128]
    float* shift = scale + 128;                     // [128]
    float* w2s   = shift + 128;                     // [128]
    float* w2d   = w2s + 128;                       // [128] ends 10153588
    float* Psum  = ws + 10153600;                   // [3200][128]
    float* Psq   = Psum + 409600;                   // [3200][128]
    float* Qsum  = Psq + 409600;                    // [32][128]
    float* Qsq   = Qsum + 4096;                     // [32][128]
    bf16*  W2t   = (bf16*)(Qsq + 4096);             // [128][128] bf16 (8192 f)
    bf16*  Wgt   = W2t + 16384;                     // [112][128] bf16 (7168 f)
    float* xf    = ws + 10996352;                   // [N][16] packed {x8,fs,fd,pad}

    // ---- bucketed CSR build + fsfd(packed xf) + weight prep (one launch) ----
    hipMemsetAsync(cnt, 0, (size_t)(N_NODES + 4) * 4, stream);   // cnt + flags
    k_fill_fsfd<<<GRID_FILL, 256, 0, stream>>>(
        src, dst, ewt, cnt, bucket, x, W1, a1s, a1d, xf,
        W2, a2s, a2d, w2s, w2d, Wg, W2t, Wgt);

    // ---- layer 1 ----
    k_sort_gather_y1<<<SG_GRID, 256, 0, stream>>>(cnt, bucket, xf, W1,
                                                  Yb, Psum, Psq);
    k_reduce_fused<<<17, 256, 0, stream>>>(Psum, Psq, SG_GRID, 100, Qsum, Qsq,
                                           gam, bet, scale, shift, flags + 0);

    // ---- layer 2 ----
    k_gemm_mfma<128, true><<<MACRO_TILES, 256, 0, stream>>>(Yb, scale, shift, W2t, Hb,
                                                            w2s, w2d, fs, fd);    // Hb = h2
    k_gather_attn_bf<<<ATT_GRID, 256, 0, stream>>>(cnt, bucket, fs, fd, Hb, Yb,
                                                   Psum, Psq);                    // Yb = y2 + stats
    k_reduce_fused<<<17, 256, 0, stream>>>(Psum, Psq, ATT_GRID, 100, Qsum, Qsq,
                                           gam, bet, scale, shift, flags + 1);

    // ---- output head ----
    k_gemm_mfma<112, false><<<MACRO_TILES, 256, 0, stream>>>(Yb, scale, shift, Wgt, Hb,
                                                             nullptr, nullptr, nullptr, nullptr);
    k_gather_out_bf<<<OUT_GRID, 256, 0, stream>>>(cnt, bucket, Hb, bg, out);
}

// Round 13
// 276.370 us; speedup vs baseline: 1.0637x; 1.0637x over previous
//
#include <hip/hip_runtime.h>
#include <hip/hip_bf16.h>

#define N_NODES 50000
#define N_EDGES 800000
#define NFEAT   8
#define NHID    128
#define NCLASS  112
#define SEG_EPS 1e-16f
#define BN_EPS  1e-5f
#define CAP     64
#define MACRO_TILES 782
#define NODE_RANGE 6250
#define FILL_CHUNK 2048
#define FILL_CHUNKS 391
#define FSFD_BLOCKS 196
#define SG_GRID 3200
#define SG_IT 4
#define ATT_GRID 3200
#define ATT_IT 4
#define OUT_GRID 3200
#define OUT_IT 4

#define FILLB (FILL_CHUNKS * 8)
#define FSFD0 FILLB
#define W2P0  (FSFD0 + FSFD_BLOCKS)
#define W2T0  (W2P0 + 64)
#define WGT0  (W2T0 + 32)
#define GRID_FILL (WGT0 + 28)

typedef __hip_bfloat16 bf16;
typedef __attribute__((ext_vector_type(8))) short short8;
typedef __attribute__((ext_vector_type(4))) float f32x4;
typedef __attribute__((ext_vector_type(4))) unsigned int u32x4;

__device__ __forceinline__ float bfbits2f(unsigned int lo16) {
    union { unsigned int u; float f; } c; c.u = lo16 << 16; return c.f;
}

__device__ __forceinline__ unsigned int pack_bf2(float a, float b) {
    union { unsigned int u; bf16 h[2]; } t;
    t.h[0] = __float2bfloat16(a);
    t.h[1] = __float2bfloat16(b);
    return t.u;
}

// ======= bucketed CSR build (XCD-partitioned) + fsfd + weight prep =======
// 8 edges/thread, edge data loaded vectorized upfront, payload precomputed.
// LESSONS LOCKED IN: (r7) nt loads regress (scattered reads need L2/L3);
// (r10) no per-block __threadfence (per-XCD L2 writeback storm, 10x regress);
// (r12) no deeper unroll/edges-per-thread (TLP > ILP here: occupancy is the
// latency hider; 16-edge variant + unroll-8 gathers cost 17us).
__global__ __launch_bounds__(256)
void k_fill_fsfd(const int* __restrict__ src, const int* __restrict__ dst,
                 const float* __restrict__ ewt,
                 int* __restrict__ cnt, unsigned int* __restrict__ bucket,
                 const float* __restrict__ x, const float* __restrict__ W1,
                 const float* __restrict__ a1s, const float* __restrict__ a1d,
                 float* __restrict__ xf,
                 const float* __restrict__ W2,
                 const float* __restrict__ a2s, const float* __restrict__ a2d,
                 float* __restrict__ w2s, float* __restrict__ w2d,
                 const float* __restrict__ Wg,
                 bf16* __restrict__ W2t, bf16* __restrict__ Wgt) {
    __shared__ float sw[16];
    __shared__ float ps[4], pd[4];
    const int t = threadIdx.x;
    if (blockIdx.x < FILLB) {
        const int range = blockIdx.x & 7;
        const int chunk = blockIdx.x >> 3;
        const int lo = range * NODE_RANGE, hi = lo + NODE_RANGE;
        const int e0 = chunk * FILL_CHUNK + t * 8;
        if (e0 >= N_EDGES) return;        // 800000 % 8 == 0
        const int4 d0 = *(const int4*)&dst[e0];
        const int4 d1 = *(const int4*)&dst[e0 + 4];
        const int4 s0 = *(const int4*)&src[e0];
        const int4 s1 = *(const int4*)&src[e0 + 4];
        const float4 w0 = *(const float4*)&ewt[e0];
        const float4 w1 = *(const float4*)&ewt[e0 + 4];
        const int dd[8] = {d0.x, d0.y, d0.z, d0.w, d1.x, d1.y, d1.z, d1.w};
        const int ss[8] = {s0.x, s0.y, s0.z, s0.w, s1.x, s1.y, s1.z, s1.w};
        const float ww[8] = {w0.x, w0.y, w0.z, w0.w, w1.x, w1.y, w1.z, w1.w};
        unsigned int pl[8];
#pragma unroll
        for (int i = 0; i < 8; i++)
            pl[i] = ((unsigned int)ss[i] << 15) |
                    (unsigned int)(ww[i] * 32767.f + 0.5f);
#pragma unroll
        for (int i = 0; i < 8; i++) {
            int d = dd[i];
            if (d < lo || d >= hi) continue;
            int slot = atomicAdd(&cnt[d], 1);
            if (slot < CAP) bucket[d * CAP + slot] = pl[i];
        }
        return;
    }
    if (blockIdx.x < W2P0) {
        const int w = t >> 6, lane = t & 63;
#pragma unroll
        for (int dd = 0; dd < 4; dd++) {
            int dot = w + dd * 4;
            int k = dot & 7;
            const float* a = (dot < 8) ? a1s : a1d;
            float v = W1[k * NHID + lane] * a[lane] + W1[k * NHID + 64 + lane] * a[64 + lane];
#pragma unroll
            for (int off = 32; off > 0; off >>= 1) v += __shfl_down(v, off);
            if (lane == 0) sw[dot] = v;
        }
        __syncthreads();
        const int i = (blockIdx.x - FSFD0) * 256 + t;
        if (i < N_NODES) {
            const float4 x0 = ((const float4*)x)[i * 2];
            const float4 x1 = ((const float4*)x)[i * 2 + 1];
            float fsv = x0.x*sw[0] + x0.y*sw[1] + x0.z*sw[2] + x0.w*sw[3]
                      + x1.x*sw[4] + x1.y*sw[5] + x1.z*sw[6] + x1.w*sw[7];
            float fdv = x0.x*sw[8] + x0.y*sw[9] + x0.z*sw[10] + x0.w*sw[11]
                      + x1.x*sw[12] + x1.y*sw[13] + x1.z*sw[14] + x1.w*sw[15];
            float4* xr = (float4*)&xf[(size_t)i * 16];
            xr[0] = x0;
            xr[1] = x1;
            xr[2] = make_float4(fsv, fdv, 0.f, 0.f);
        }
        return;
    }
    if (blockIdx.x < W2T0) {
        const int k = (blockIdx.x - W2P0) * 2 + (t >> 7);
        const int n = t & 127;
        float wv = W2[k * NHID + n];
        float vs = wv * a2s[n], vd = wv * a2d[n];
#pragma unroll
        for (int off = 32; off > 0; off >>= 1) { vs += __shfl_down(vs, off); vd += __shfl_down(vd, off); }
        const int wid = t >> 6;
        if ((t & 63) == 0) { ps[wid] = vs; pd[wid] = vd; }
        __syncthreads();
        if ((t & 127) == 0) { w2s[k] = ps[wid] + ps[wid + 1]; w2d[k] = pd[wid] + pd[wid + 1]; }
        return;
    }
    if (blockIdx.x < WGT0) {
        const int n = (blockIdx.x - W2T0) * 4 + (t >> 6);
        const int k2 = (t & 63) * 2;
        *(unsigned int*)&W2t[n * 128 + k2] = pack_bf2(W2[k2 * NHID + n], W2[(k2 + 1) * NHID + n]);
        return;
    }
    const int n = (blockIdx.x - WGT0) * 4 + (t >> 6);
    const int k2 = (t & 63) * 2;
    *(unsigned int*)&Wgt[n * 128 + k2] = pack_bf2(Wg[k2 * NCLASS + n], Wg[(k2 + 1) * NCLASS + n]);
}

// ===== sort + gather + y1 + BN partials, grid-strided 3200 x 4 iters =====
__global__ __launch_bounds__(256)
void k_sort_gather_y1(const int* __restrict__ cnt, unsigned int* __restrict__ bucket,
                      const float* __restrict__ xf, const float* __restrict__ W1,
                      bf16* __restrict__ y1,
                      float* __restrict__ Psum, float* __restrict__ Psq) {
    const int xcd = blockIdx.x & 7;
    const int wb  = blockIdx.x >> 3;
    const int t = threadIdx.x;
    const int q = t >> 6;
    const int lane = t & 63;
    float w1c0[8], w1c1[8];
#pragma unroll
    for (int k = 0; k < 8; k++) {
        const float2 wv = *(const float2*)&W1[k * NHID + 2 * lane];
        w1c0[k] = wv.x; w1c1[k] = wv.y;
    }
    float ls0 = 0.f, ls1 = 0.f, lq0 = 0.f, lq1 = 0.f;
    for (int it = 0; it < SG_IT; it++) {
        const int ni = (wb + it * 400) * 4 + q;
        if (ni >= NODE_RANGE) continue;
        const int d = xcd * NODE_RANGE + ni;
        const int deg = min(cnt[d], CAP);
        unsigned int v = (lane < deg) ? bucket[d * CAP + lane] : 0xFFFFFFFFu;
#pragma unroll
        for (int k = 2; k <= 64; k <<= 1) {
#pragma unroll
            for (int s = k >> 1; s > 0; s >>= 1) {
                unsigned int o = (unsigned int)__shfl_xor((int)v, s);
                bool keepmin = ((lane & s) == 0) == ((lane & k) == 0);
                v = keepmin ? min(v, o) : max(v, o);
            }
        }
        if (lane < deg) bucket[d * CAP + lane] = v;
        const int epair = lane >> 1;
        const int half  = lane & 1;
        const float fdd = xf[(size_t)d * 16 + 9];
        float4 acc = {0.f, 0.f, 0.f, 0.f};
        float den = 0.f;
        for (int base = 0; base < deg; base += 32) {
            int e = base + epair;
            unsigned int u = (unsigned int)__shfl((int)v, e);
            if (e < deg) {
                int s = u >> 15;
                const float4 xv = *(const float4*)&xf[(size_t)s * 16 + half * 4];
                float fsv = xf[(size_t)s * 16 + 8];       // same 64B line
                float f = fsv + fdd;
                float lr = f > 0.f ? f : 0.2f * f;
                float c = __expf(-lr);
                if (half == 0) den += c;
                acc.x += c * xv.x; acc.y += c * xv.y; acc.z += c * xv.z; acc.w += c * xv.w;
            }
        }
#pragma unroll
        for (int off = 2; off < 64; off <<= 1) {
            acc.x += __shfl_xor(acc.x, off);
            acc.y += __shfl_xor(acc.y, off);
            acc.z += __shfl_xor(acc.z, off);
            acc.w += __shfl_xor(acc.w, off);
            den   += __shfl_xor(den, off);
        }
        den += __shfl_xor(den, 1);
        float4 oth;
        oth.x = __shfl_xor(acc.x, 1);
        oth.y = __shfl_xor(acc.y, 1);
        oth.z = __shfl_xor(acc.z, 1);
        oth.w = __shfl_xor(acc.w, 1);
        const float r = 1.f / (den + SEG_EPS);
        float xa[8];
        if ((lane & 1) == 0) {
            xa[0]=acc.x*r; xa[1]=acc.y*r; xa[2]=acc.z*r; xa[3]=acc.w*r;
            xa[4]=oth.x*r; xa[5]=oth.y*r; xa[6]=oth.z*r; xa[7]=oth.w*r;
        } else {
            xa[0]=oth.x*r; xa[1]=oth.y*r; xa[2]=oth.z*r; xa[3]=oth.w*r;
            xa[4]=acc.x*r; xa[5]=acc.y*r; xa[6]=acc.z*r; xa[7]=acc.w*r;
        }
        float v0 = 0.f, v1 = 0.f;
#pragma unroll
        for (int k = 0; k < 8; k++) {
            v0 += xa[k] * w1c0[k];
            v1 += xa[k] * w1c1[k];
        }
        ((unsigned int*)y1)[(size_t)d * 64 + lane] = pack_bf2(v0, v1);
        ls0 += v0; lq0 += v0 * v0;
        ls1 += v1; lq1 += v1 * v1;
    }
    __shared__ float sred[4][64][2];
    sred[q][lane][0] = ls0;
    sred[q][lane][1] = ls1;
    __syncthreads();
    if (t < 128) {
        int ln = t >> 1, cp = t & 1;
        Psum[blockIdx.x * 128 + t] =
            ((sred[0][ln][cp] + sred[1][ln][cp]) + sred[2][ln][cp]) + sred[3][ln][cp];
    }
    __syncthreads();
    sred[q][lane][0] = lq0;
    sred[q][lane][1] = lq1;
    __syncthreads();
    if (t < 128) {
        int ln = t >> 1, cp = t & 1;
        Psq[blockIdx.x * 128 + t] =
            ((sred[0][ln][cp] + sred[1][ln][cp]) + sred[2][ln][cp]) + sred[3][ln][cp];
    }
}

// ===== fused BN reduction (SEPARATE dispatch): 16 workers + 1 finalizer =====
__global__ __launch_bounds__(256)
void k_reduce_fused(const float* __restrict__ Psum, const float* __restrict__ Psq,
                    int nIn, int chunk,
                    float* __restrict__ Qsum, float* __restrict__ Qsq,
                    const float* __restrict__ gamma, const float* __restrict__ beta,
                    float* __restrict__ scale, float* __restrict__ shift,
                    int* __restrict__ flag) {
    const int t = threadIdx.x;
    if (blockIdx.x < 16) {
        const int j = t & 127;
        const int h = t >> 7;
        const int u = blockIdx.x * 2 + h;
        const int b0 = u * chunk, b1 = min(b0 + chunk, nIn);
        float s = 0.f, q = 0.f;
#pragma unroll 8
        for (int b = b0; b < b1; b++) {
            s += Psum[b * 128 + j];
            q += Psq[b * 128 + j];
        }
        Qsum[u * 128 + j] = s;
        Qsq[u * 128 + j] = q;
        __threadfence();
        __syncthreads();
        if (t == 0) atomicAdd(flag, 1);
        return;
    }
    if (t == 0) { while (atomicAdd(flag, 0) < 16) { } }
    __syncthreads();
    __threadfence();
    const int j = t & 127;
    const int g = t >> 7;
    float s = 0.f, q = 0.f;
#pragma unroll
    for (int u = g * 16; u < g * 16 + 16; u++) {
        s += Qsum[u * 128 + j];
        q += Qsq[u * 128 + j];
    }
    __shared__ float Ls[2][128], Lq[2][128];
    Ls[g][j] = s; Lq[g][j] = q;
    __syncthreads();
    if (g == 0) {
        float st = Ls[0][j] + Ls[1][j];
        float qt = Lq[0][j] + Lq[1][j];
        float mu = st * (1.f / N_NODES);
        float var = qt * (1.f / N_NODES) - mu * mu;
        float rs = rsqrtf(var + BN_EPS);
        float ga = gamma[j];
        scale[j] = rs * ga;
        shift[j] = beta[j] - mu * rs * ga;
    }
    __syncthreads();
    if (t == 0) atomicExch(flag, 0);
}

// ===== MFMA GEMM v2: direct-A from global, prestaged bf16 B =====
template<int NCV, bool ATT>
__global__ __launch_bounds__(256)
void k_gemm_mfma(const bf16* __restrict__ Yin,
                 const float* __restrict__ scale, const float* __restrict__ shift,
                 const bf16* __restrict__ Wt_g,
                 bf16* __restrict__ hout,
                 const float* __restrict__ w2s, const float* __restrict__ w2d,
                 float* __restrict__ fs, float* __restrict__ fd) {
    constexpr int NT = NCV / 16;
    __shared__ bf16 Wt[NCV * 136];
    __shared__ float scb[128], shb[128];
    const int t = threadIdx.x;
    for (int idx = t; idx < NCV * 16; idx += 256) {
        int n = idx >> 4, c = idx & 15;
        *(u32x4*)&Wt[n * 136 + c * 8] = *(const u32x4*)&Wt_g[n * 128 + c * 8];
    }
    if (t < 128) { scb[t] = scale[t]; shb[t] = shift[t]; }
    const int lane = t & 63;
    const int m16 = lane & 15;
    const int g = lane >> 4;
    const int rg = t >> 6;
    short8 attb[4];
    if constexpr (ATT) {
#pragma unroll
        for (int kk = 0; kk < 4; kk++) {
            union { short8 s; unsigned int u[4]; } pk;
            if (m16 < 2) {
                const float* wv = (m16 == 0) ? w2s : w2d;
                const float4 f0 = *(const float4*)&wv[kk * 32 + g * 8];
                const float4 f1 = *(const float4*)&wv[kk * 32 + g * 8 + 4];
                pk.u[0] = pack_bf2(f0.x, f0.y);
                pk.u[1] = pack_bf2(f0.z, f0.w);
                pk.u[2] = pack_bf2(f1.x, f1.y);
                pk.u[3] = pack_bf2(f1.z, f1.w);
            } else {
                pk.u[0] = pk.u[1] = pk.u[2] = pk.u[3] = 0u;
            }
            attb[kk] = pk.s;
        }
    }
    __syncthreads();

    const int row0 = blockIdx.x * 64;
    const int arow = row0 + rg * 16 + m16;
    const bool rok = arow < N_NODES;
    f32x4 acc[NT];
#pragma unroll
    for (int c = 0; c < NT; c++) acc[c] = (f32x4){0.f, 0.f, 0.f, 0.f};
    f32x4 accA = (f32x4){0.f, 0.f, 0.f, 0.f};
#pragma unroll
    for (int kk = 0; kk < 4; kk++) {
        u32x4 u4 = rok
            ? *(const u32x4*)&((const unsigned int*)Yin)[(size_t)arow * 64 + kk * 16 + g * 4]
            : (u32x4){0u, 0u, 0u, 0u};
        const float4 s0 = *(const float4*)&scb[kk * 32 + g * 8];
        const float4 s1 = *(const float4*)&scb[kk * 32 + g * 8 + 4];
        const float4 h0 = *(const float4*)&shb[kk * 32 + g * 8];
        const float4 h1 = *(const float4*)&shb[kk * 32 + g * 8 + 4];
        const float scv[8] = {s0.x, s0.y, s0.z, s0.w, s1.x, s1.y, s1.z, s1.w};
        const float shv[8] = {h0.x, h0.y, h0.z, h0.w, h1.x, h1.y, h1.z, h1.w};
        union { short8 s; unsigned int u[4]; } A;
#pragma unroll
        for (int fq = 0; fq < 4; fq++) {
            unsigned int u = u4[fq];
            float v0 = bfbits2f(u & 0xFFFF) * scv[2*fq]   + shv[2*fq];   v0 = v0 > 0.f ? v0 : 0.01f * v0;
            float v1 = bfbits2f(u >> 16)    * scv[2*fq+1] + shv[2*fq+1]; v1 = v1 > 0.f ? v1 : 0.01f * v1;
            A.u[fq] = pack_bf2(v0, v1);
        }
#pragma unroll
        for (int c = 0; c < NT; c++) {
            short8 bfr = *(const short8*)&Wt[(c * 16 + m16) * 136 + kk * 32 + g * 8];
            acc[c] = __builtin_amdgcn_mfma_f32_16x16x32_bf16(A.s, bfr, acc[c], 0, 0, 0);
        }
        if constexpr (ATT)
            accA = __builtin_amdgcn_mfma_f32_16x16x32_bf16(A.s, attb[kk], accA, 0, 0, 0);
    }
    const int orow = row0 + rg * 16 + g * 4;
#pragma unroll
    for (int c = 0; c < NT; c++) {
#pragma unroll
        for (int r = 0; r < 4; r++) {
            int grow = orow + r;
            if (grow < N_NODES)
                hout[(size_t)grow * 128 + c * 16 + m16] = __float2bfloat16(acc[c][r]);
        }
    }
    if constexpr (ATT) {
        if (m16 < 2) {
            float* o = (m16 == 0) ? fs : fd;
#pragma unroll
            for (int r = 0; r < 4; r++) {
                int grow = orow + r;
                if (grow < N_NODES) o[grow] = accA[r];
            }
        }
    }
}

// ===== attention gather, 4-edges-per-wave dwordx4 + fused BN stats =====
__global__ __launch_bounds__(256)
void k_gather_attn_bf(const int* __restrict__ cnt, const unsigned int* __restrict__ bucket,
                      const float* __restrict__ fs, const float* __restrict__ fd,
                      const bf16* __restrict__ h, bf16* __restrict__ y,
                      float* __restrict__ Psum, float* __restrict__ Psq) {
    const int xcd = blockIdx.x & 7;
    const int wb  = blockIdx.x >> 3;
    const int t = threadIdx.x;
    const int q = t >> 6;
    const int lane = t & 63;
    const int grp = lane >> 4;
    const int l = lane & 15;
    __shared__ int s_idx[4][CAP];
    __shared__ float s_e[4][CAP];
    __shared__ float sred[4][16][8];
    float ls[8], lq[8];
#pragma unroll
    for (int i = 0; i < 8; i++) { ls[i] = 0.f; lq[i] = 0.f; }

    for (int it = 0; it < ATT_IT; it++) {
        const int ni = (wb + it * 400) * 4 + q;
        if (ni >= NODE_RANGE) continue;
        const int d = xcd * NODE_RANGE + ni;
        const int deg = min(cnt[d], CAP);
        const float fdd = fd[d];
        if (lane < deg) {
            int s = bucket[d * CAP + lane] >> 15;
            float f = fs[s] + fdd;
            float lr = f > 0.f ? f : 0.2f * f;
            s_idx[q][lane] = s;
            s_e[q][lane] = __expf(-lr);
        }
        float a[8];
#pragma unroll
        for (int i = 0; i < 8; i++) a[i] = 0.f;
        float den = 0.f;
#pragma unroll 4
        for (int base = 0; base < deg; base += 4) {
            int k = base + grp;
            bool ev = k < deg;
            int kk = ev ? k : 0;
            float e = ev ? s_e[q][kk] : 0.f;
            int sidx = s_idx[q][kk];
            u32x4 u4 = *(const u32x4*)&((const unsigned int*)h)[(size_t)sidx * 64 + l * 4];
            den += e;
#pragma unroll
            for (int fq = 0; fq < 4; fq++) {
                unsigned int u = u4[fq];
                a[2*fq]   += e * bfbits2f(u & 0xFFFF);
                a[2*fq+1] += e * bfbits2f(u >> 16);
            }
        }
#pragma unroll
        for (int off = 16; off < 64; off <<= 1) {
#pragma unroll
            for (int i = 0; i < 8; i++) a[i] += __shfl_xor(a[i], off);
            den += __shfl_xor(den, off);
        }
        float r = 1.f / (den + SEG_EPS);
        if (lane < 16) {
            u32x4 pk;
#pragma unroll
            for (int fq = 0; fq < 4; fq++) {
                float v0 = a[2*fq] * r, v1 = a[2*fq+1] * r;
                pk[fq] = pack_bf2(v0, v1);
                ls[2*fq] += v0;   lq[2*fq] += v0 * v0;
                ls[2*fq+1] += v1; lq[2*fq+1] += v1 * v1;
            }
            *(u32x4*)&((unsigned int*)y)[(size_t)d * 64 + l * 4] = pk;
        }
    }
    if (lane < 16) {
#pragma unroll
        for (int i = 0; i < 8; i++) sred[q][l][i] = ls[i];
    }
    __syncthreads();
    if (t < 128) {
        int l16 = t >> 3, i8 = t & 7;
        Psum[blockIdx.x * 128 + t] =
            ((sred[0][l16][i8] + sred[1][l16][i8]) + sred[2][l16][i8]) + sred[3][l16][i8];
    }
    __syncthreads();
    if (lane < 16) {
#pragma unroll
        for (int i = 0; i < 8; i++) sred[q][l][i] = lq[i];
    }
    __syncthreads();
    if (t < 128) {
        int l16 = t >> 3, i8 = t & 7;
        Psq[blockIdx.x * 128 + t] =
            ((sred[0][l16][i8] + sred[1][l16][i8]) + sred[2][l16][i8]) + sred[3][l16][i8];
    }
}

// ===== final gather + epilogue: grid-strided 3200 x 4, 14-chunk loads =====
__global__ __launch_bounds__(256)
void k_gather_out_bf(const int* __restrict__ cnt, const unsigned int* __restrict__ bucket,
                     const bf16* __restrict__ sup, const float* __restrict__ bg,
                     float* __restrict__ out) {
    const int xcd = blockIdx.x & 7;
    const int wb  = blockIdx.x >> 3;
    const int t = threadIdx.x;
    const int q = t >> 6;
    const int lane = t & 63;
    const int grp = lane >> 4;
    const int l = lane & 15;
    __shared__ int s_idx[4][CAP];
    __shared__ float s_w[4][CAP];
    for (int it = 0; it < OUT_IT; it++) {
        const int ni = (wb + it * 400) * 4 + q;
        if (ni >= NODE_RANGE) continue;
        const int d = xcd * NODE_RANGE + ni;
        const int deg = min(cnt[d], CAP);
        if (lane < deg) {
            unsigned int b = bucket[d * CAP + lane];
            s_idx[q][lane] = b >> 15;
            s_w[q][lane] = (float)(b & 0x7FFF) * (1.f / (32767.f * 3.f));
        }
        float a[8];
#pragma unroll
        for (int i = 0; i < 8; i++) a[i] = 0.f;
#pragma unroll 4
        for (int base = 0; base < deg; base += 4) {
            int k = base + grp;
            bool ev = k < deg;
            int kk = ev ? k : 0;
            float w = ev ? s_w[q][kk] : 0.f;
            int sidx = s_idx[q][kk];
            u32x4 u4 = (l < 14)
                ? *(const u32x4*)&((const unsigned int*)sup)[(size_t)sidx * 64 + l * 4]
                : (u32x4){0u, 0u, 0u, 0u};
#pragma unroll
            for (int fq = 0; fq < 4; fq++) {
                unsigned int u = u4[fq];
                a[2*fq]   += w * bfbits2f(u & 0xFFFF);
                a[2*fq+1] += w * bfbits2f(u >> 16);
            }
        }
#pragma unroll
        for (int off = 16; off < 64; off <<= 1) {
#pragma unroll
            for (int i = 0; i < 8; i++) a[i] += __shfl_xor(a[i], off);
        }
        if (l < 14) {
            u32x4 us = *(const u32x4*)&((const unsigned int*)sup)[(size_t)d * 64 + l * 4];
            const float4 b0 = *(const float4*)&bg[l * 8];
            const float4 b1 = *(const float4*)&bg[l * 8 + 4];
            float4 o0, o1;
            o0.x = a[0] + bfbits2f(us[0] & 0xFFFF) * (2.f/3.f) + b0.x;
            o0.y = a[1] + bfbits2f(us[0] >> 16)    * (2.f/3.f) + b0.y;
            o0.z = a[2] + bfbits2f(us[1] & 0xFFFF) * (2.f/3.f) + b0.z;
            o0.w = a[3] + bfbits2f(us[1] >> 16)    * (2.f/3.f) + b0.w;
            o1.x = a[4] + bfbits2f(us[2] & 0xFFFF) * (2.f/3.f) + b1.x;
            o1.y = a[5] + bfbits2f(us[2] >> 16)    * (2.f/3.f) + b1.y;
            o1.z = a[6] + bfbits2f(us[3] & 0xFFFF) * (2.f/3.f) + b1.z;
            o1.w = a[7] + bfbits2f(us[3] >> 16)    * (2.f/3.f) + b1.w;
            *(float4*)&out[(size_t)d * NCLASS + l * 8]     = o0;
            *(float4*)&out[(size_t)d * NCLASS + l * 8 + 4] = o1;
        }
    }
}

extern "C" void kernel_launch(void* const* d_in, const int* in_sizes, int n_in,
                              void* d_out, int out_size, void* d_ws, size_t ws_size,
                              hipStream_t stream) {
    const float* x    = (const float*)d_in[0];
    const int*   ei   = (const int*)d_in[1];
    const float* ewt  = (const float*)d_in[2];
    const float* W1   = (const float*)d_in[3];
    const float* a1s  = (const float*)d_in[4];
    const float* a1d  = (const float*)d_in[5];
    const float* W2   = (const float*)d_in[6];
    const float* a2s  = (const float*)d_in[7];
    const float* a2d  = (const float*)d_in[8];
    const float* gam  = (const float*)d_in[9];
    const float* bet  = (const float*)d_in[10];
    const float* Wg   = (const float*)d_in[11];
    const float* bg   = (const float*)d_in[12];
    float* out = (float*)d_out;

    const int* src = ei;
    const int* dst = ei + N_EDGES;

    float* ws    = (float*)d_ws;
    bf16*  Yb    = (bf16*)ws;                       // [N,128] bf16 (y1, then y2)
    bf16*  Hb    = (bf16*)(ws + 3203072);           // [N,128] bf16 (h2 / support)
    unsigned int* bucket = (unsigned int*)(ws + 6403072);   // [N*64] packed
    float* fs    = ws + 10003072;                   // [N]
    float* fd    = ws + 10053072;                   // [N]
    int*   cnt   = (int*)(ws + 10103072);           // [N]
    int*   flags = (int*)(ws + 10153072);           // [4] (covered by memset)
    float* scale = ws + 10153076;                   // [128]
    float* shift = scale + 128;                     // [128]
    float* w2s   = shift + 128;                     // [128]
    float* w2d   = w2s + 128;                       // [128] ends 10153588
    float* Psum  = ws + 10153600;                   // [3200][128]
    float* Psq   = Psum + 409600;                   // [3200][128]
    float* Qsum  = Psq + 409600;                    // [32][128]
    float* Qsq   = Qsum + 4096;                     // [32][128]
    bf16*  W2t   = (bf16*)(Qsq + 4096);             // [128][128] bf16 (8192 f)
    bf16*  Wgt   = W2t + 16384;                     // [112][128] bf16 (7168 f)
    float* xf    = ws + 10996352;                   // [N][16] packed {x8,fs,fd,pad}

    // ---- bucketed CSR build + fsfd(packed xf) + weight prep (one launch) ----
    hipMemsetAsync(cnt, 0, (size_t)(N_NODES + 4) * 4, stream);   // cnt + flags
    k_fill_fsfd<<<GRID_FILL, 256, 0, stream>>>(
        src, dst, ewt, cnt, bucket, x, W1, a1s, a1d, xf,
        W2, a2s, a2d, w2s, w2d, Wg, W2t, Wgt);

    // ---- layer 1 ----
    k_sort_gather_y1<<<SG_GRID, 256, 0, stream>>>(cnt, bucket, xf, W1,
                                                  Yb, Psum, Psq);
    k_reduce_fused<<<17, 256, 0, stream>>>(Psum, Psq, SG_GRID, 100, Qsum, Qsq,
                                           gam, bet, scale, shift, flags + 0);

    // ---- layer 2 ----
    k_gemm_mfma<128, true><<<MACRO_TILES, 256, 0, stream>>>(Yb, scale, shift, W2t, Hb,
                                                            w2s, w2d, fs, fd);    // Hb = h2
    k_gather_attn_bf<<<ATT_GRID, 256, 0, stream>>>(cnt, bucket, fs, fd, Hb, Yb,
                                                   Psum, Psq);                    // Yb = y2 + stats
    k_reduce_fused<<<17, 256, 0, stream>>>(Psum, Psq, ATT_GRID, 100, Qsum, Qsq,
                                           gam, bet, scale, shift, flags + 1);

    // ---- output head ----
    k_gemm_mfma<112, false><<<MACRO_TILES, 256, 0, stream>>>(Yb, scale, shift, Wgt, Hb,
                                                             nullptr, nullptr, nullptr, nullptr);
    k_gather_out_bf<<<OUT_GRID, 256, 0, stream>>>(cnt, bucket, Hb, bg, out);
}